// Round 2
// baseline (550.853 us; speedup 1.0000x reference)
//
#include <hip/hip_runtime.h>
#include <hip/hip_bf16.h>
#include <math.h>

// MemoryReader: B=16 H=8 M=64 K=32 R=65536 D_IN=512, OUT_DIM=520
// Outputs (FLOAT32, concatenated): flat_reads[16,512] | read_weights[16,8,32] |
//                                  read_indices[16,8,32] | read_strengths[16,8]
// ws layout (bytes): [0,32768) scaled keys f32; [32768,33280) strengths f32;
//                    [65536, +2MiB) candidate vals f32; then +2MiB candidate idx u32.

#define NB 16
#define NH 8
#define NM 64
#define NK 32
#define NR 65536
#define NDIN 512
#define NOUT 520
#define CHUNK 512
#define NCHUNK 128      // R / CHUNK
#define CAP 160         // k_score binary-search count upper target
#define CAP2 224        // k_final binary-search count upper target
#define SORTN 256       // collection capacity / bitonic size

#define OFF_READS 0
#define OFF_W 8192
#define OFF_I 12288
#define OFF_S 16384

// In-LDS bitonic sort of SORTN (val,idx) pairs, descending by val, ties by ascending idx.
__device__ __forceinline__ void bitonic256(float* cv, unsigned* ci, int t) {
  for (int size = 2; size <= SORTN; size <<= 1) {
    for (int stride = size >> 1; stride > 0; stride >>= 1) {
      __syncthreads();
      int j = t ^ stride;
      if (j > t) {
        float vi = cv[t], vj = cv[j];
        unsigned ii = ci[t], ij = ci[j];
        bool iFirst = (vi > vj) || (vi == vj && ii < ij); // i ranks before j (desc order)
        bool up = ((t & size) == 0);
        if (up != iFirst) { cv[t] = vj; cv[j] = vi; ci[t] = ij; ci[j] = ii; }
      }
    }
  }
  __syncthreads();
}

// Kernel 1: flat = x @ W^T + b; normalize keys per (b,h); emit strengths.
__global__ __launch_bounds__(512) void k_prep(
    const float* __restrict__ x, const float* __restrict__ W,
    const float* __restrict__ bias, float* __restrict__ sk_ws,
    float* __restrict__ str_ws, float* __restrict__ dout) {
  const int b = blockIdx.x, t = threadIdx.x;
  __shared__ float4 xs4[NDIN / 4];
  __shared__ float flat[NOUT];
  if (t < NDIN / 4) xs4[t] = reinterpret_cast<const float4*>(x + (size_t)b * NDIN)[t];
  __syncthreads();
  {
    const float4* Wr = reinterpret_cast<const float4*>(W + (size_t)t * NDIN);
    float acc = 0.f;
    for (int i = 0; i < NDIN / 4; ++i) {
      float4 w4 = Wr[i], v = xs4[i];
      acc += w4.x * v.x + w4.y * v.y + w4.z * v.z + w4.w * v.w;
    }
    flat[t] = acc + bias[t];
  }
  if (t < NOUT - NDIN) {
    const int j = NDIN + t;
    const float4* Wr = reinterpret_cast<const float4*>(W + (size_t)j * NDIN);
    float acc = 0.f;
    for (int i = 0; i < NDIN / 4; ++i) {
      float4 w4 = Wr[i], v = xs4[i];
      acc += w4.x * v.x + w4.y * v.y + w4.z * v.z + w4.w * v.w;
    }
    flat[j] = acc + bias[j];
  }
  __syncthreads();
  // t = h*64 + m; each 64-lane wave is exactly one head h.
  float v = flat[t];
  float ss = v * v;
  #pragma unroll
  for (int off = 32; off >= 1; off >>= 1) ss += __shfl_xor(ss, off, 64);
  float rn = 1.0f / fmaxf(sqrtf(ss), 1e-12f);
  sk_ws[(size_t)b * NDIN + t] = v * rn;
  if (t < NH) {
    float s = flat[NDIN + t];
    str_ws[b * NH + t] = s;
    dout[OFF_S + b * NH + t] = s;
  }
}

// Kernel 2: per (b, 512-row chunk): scores for all 8 heads, then exact
// chunk-local sorted top-32 per head via value-domain binary search + bitonic.
__global__ __launch_bounds__(256) void k_score(
    const float* __restrict__ mem, const float* __restrict__ sk_ws,
    const float* __restrict__ str_ws, float* __restrict__ cv_ws,
    unsigned* __restrict__ ci_ws) {
  const int b = blockIdx.x >> 7;
  const int chunk = blockIdx.x & 127;
  const int base = chunk * CHUNK;
  const int t = threadIdx.x;
  const int lane = t & 63, wid = t >> 6;

  __shared__ float4 sk4[NH * NM / 4];  // 128 float4 = 2 KB
  __shared__ float str[NH];
  __shared__ float sc[CHUNK * NH];     // 16 KB
  __shared__ float cv[SORTN];
  __shared__ unsigned ci[SORTN];
  __shared__ float red[8];
  __shared__ unsigned ucnt;

  if (t < 128) sk4[t] = reinterpret_cast<const float4*>(sk_ws + (size_t)b * NDIN)[t];
  if (t < NH) str[t] = str_ws[b * NH + t];
  __syncthreads();

  // ---- score phase: 2 rows per thread ----
  {
    const float4* m0 = reinterpret_cast<const float4*>(mem + ((size_t)b * NR + base + t) * NM);
    const float4* m1 = reinterpret_cast<const float4*>(mem + ((size_t)b * NR + base + t + 256) * NM);
    float d0a[NH], d1a[NH];
    #pragma unroll
    for (int h = 0; h < NH; ++h) { d0a[h] = 0.f; d1a[h] = 0.f; }
    float ss0 = 0.f, ss1 = 0.f;
    #pragma unroll
    for (int i = 0; i < NM / 4; ++i) {
      float4 va = m0[i], vb = m1[i];
      ss0 += va.x * va.x + va.y * va.y + va.z * va.z + va.w * va.w;
      ss1 += vb.x * vb.x + vb.y * vb.y + vb.z * vb.z + vb.w * vb.w;
      #pragma unroll
      for (int h = 0; h < NH; ++h) {
        float4 s4 = sk4[h * (NM / 4) + i];
        d0a[h] += va.x * s4.x + va.y * s4.y + va.z * s4.z + va.w * s4.w;
        d1a[h] += vb.x * s4.x + vb.y * s4.y + vb.z * s4.z + vb.w * s4.w;
      }
    }
    float rn0 = 1.0f / fmaxf(sqrtf(ss0), 1e-12f);
    float rn1 = 1.0f / fmaxf(sqrtf(ss1), 1e-12f);
    #pragma unroll
    for (int h = 0; h < NH; ++h) {
      sc[t * NH + h] = str[h] * (d0a[h] * rn0);
      sc[(t + 256) * NH + h] = str[h] * (d1a[h] * rn1);
    }
  }
  __syncthreads();

  // ---- per-head exact top-32 of this chunk ----
  for (int h = 0; h < NH; ++h) {
    float va = sc[t * NH + h];
    float vb = sc[(t + 256) * NH + h];
    // block min/max
    float mx = fmaxf(va, vb), mn = fminf(va, vb);
    #pragma unroll
    for (int off = 32; off >= 1; off >>= 1) {
      mx = fmaxf(mx, __shfl_xor(mx, off, 64));
      mn = fminf(mn, __shfl_xor(mn, off, 64));
    }
    if (lane == 0) { red[wid] = mx; red[4 + wid] = mn; }
    __syncthreads();
    float bmax = fmaxf(fmaxf(red[0], red[1]), fmaxf(red[2], red[3]));
    float bmin = fminf(fminf(red[4], red[5]), fminf(red[6], red[7]));
    __syncthreads();

    // binary search on value for threshold T with count(>T) in [32, CAP]
    float lo = bmin - 1.0f, hi = bmax;
    float T = lo;
    bool found = false;
    for (int it = 0; it < 48; ++it) {
      float mid = 0.5f * (lo + hi);
      if (!(mid > lo && mid < hi)) break;
      if (t == 0) ucnt = 0u;
      __syncthreads();
      unsigned c = (va > mid ? 1u : 0u) + (vb > mid ? 1u : 0u);
      #pragma unroll
      for (int off = 32; off >= 1; off >>= 1) c += __shfl_xor(c, off, 64);
      if (lane == 0) atomicAdd(&ucnt, c);
      __syncthreads();
      unsigned cnt = ucnt;
      __syncthreads();
      if (cnt >= NK) {
        lo = mid;
        if (cnt <= CAP) { T = mid; found = true; break; }
      } else {
        hi = mid;
      }
    }
    if (!found) T = lo;  // invariant: count(>lo) >= 32

    // collect all elements > T
    if (t == 0) ucnt = 0u;
    __syncthreads();
    if (va > T) {
      unsigned p = atomicAdd(&ucnt, 1u);
      if (p < SORTN) { cv[p] = va; ci[p] = (unsigned)(base + t); }
    }
    if (vb > T) {
      unsigned p = atomicAdd(&ucnt, 1u);
      if (p < SORTN) { cv[p] = vb; ci[p] = (unsigned)(base + t + 256); }
    }
    __syncthreads();
    unsigned cnt = ucnt < SORTN ? ucnt : (unsigned)SORTN;
    if ((unsigned)t >= cnt) { cv[t] = -INFINITY; ci[t] = 0x7FFFFFFFu; }
    bitonic256(cv, ci, t);  // begins with __syncthreads()

    if (t < NK) {
      size_t o = (((size_t)(b * NH + h)) * NCHUNK + chunk) * NK + t;
      cv_ws[o] = cv[t];
      ci_ws[o] = ci[t];
    }
    __syncthreads();
  }
}

// Kernel 3: per (b,h): exact global top-32 over the 4096 chunk candidates
// (held in registers) via value-domain binary search + bitonic sort, then
// softmax, gather memory rows, write remaining outputs.
__global__ __launch_bounds__(256) void k_final(
    const float* __restrict__ mem, const float* __restrict__ cv_ws,
    const unsigned* __restrict__ ci_ws, float* __restrict__ dout) {
  const int bh = blockIdx.x;
  const int b = bh >> 3;
  const int t = threadIdx.x;
  const int lane = t & 63, wid = t >> 6;

  __shared__ float cv[SORTN];
  __shared__ unsigned ci[SORTN];
  __shared__ float red[8];
  __shared__ unsigned ucnt;
  __shared__ float wts[NK];
  __shared__ unsigned widx[NK];

  const float* CV = cv_ws + (size_t)bh * (NCHUNK * NK);
  const unsigned* CI = ci_ws + (size_t)bh * (NCHUNK * NK);

  // All 4096 candidates in registers: 16 (val,idx) per thread, coalesced.
  float v[16];
  unsigned vi[16];
  #pragma unroll
  for (int i = 0; i < 16; ++i) {
    v[i] = CV[i * 256 + t];
    vi[i] = CI[i * 256 + t];
  }

  float mx = v[0], mn = v[0];
  #pragma unroll
  for (int i = 1; i < 16; ++i) { mx = fmaxf(mx, v[i]); mn = fminf(mn, v[i]); }
  #pragma unroll
  for (int off = 32; off >= 1; off >>= 1) {
    mx = fmaxf(mx, __shfl_xor(mx, off, 64));
    mn = fminf(mn, __shfl_xor(mn, off, 64));
  }
  if (lane == 0) { red[wid] = mx; red[4 + wid] = mn; }
  __syncthreads();
  float bmax = fmaxf(fmaxf(red[0], red[1]), fmaxf(red[2], red[3]));
  float bmin = fminf(fminf(red[4], red[5]), fminf(red[6], red[7]));
  __syncthreads();

  // binary search for T with count(>T) in [32, CAP2]
  float lo = bmin - 1.0f, hi = bmax;
  float T = lo;
  bool found = false;
  for (int it = 0; it < 60; ++it) {
    float mid = 0.5f * (lo + hi);
    if (!(mid > lo && mid < hi)) break;
    if (t == 0) ucnt = 0u;
    __syncthreads();
    unsigned c = 0;
    #pragma unroll
    for (int i = 0; i < 16; ++i) c += (v[i] > mid) ? 1u : 0u;
    #pragma unroll
    for (int off = 32; off >= 1; off >>= 1) c += __shfl_xor(c, off, 64);
    if (lane == 0) atomicAdd(&ucnt, c);
    __syncthreads();
    unsigned cnt = ucnt;
    __syncthreads();
    if (cnt >= NK) {
      lo = mid;
      if (cnt <= CAP2) { T = mid; found = true; break; }
    } else {
      hi = mid;
    }
  }
  if (!found) T = lo;  // count(>lo) >= 32 invariant

  if (t == 0) ucnt = 0u;
  __syncthreads();
  #pragma unroll
  for (int i = 0; i < 16; ++i) {
    if (v[i] > T) {
      unsigned p = atomicAdd(&ucnt, 1u);
      if (p < SORTN) { cv[p] = v[i]; ci[p] = vi[i]; }
    }
  }
  __syncthreads();
  unsigned cnt = ucnt < SORTN ? ucnt : (unsigned)SORTN;
  if ((unsigned)t >= cnt) { cv[t] = -INFINITY; ci[t] = 0x7FFFFFFFu; }
  bitonic256(cv, ci, t);

  // softmax over the sorted top-32 (cv[0] is the max)
  if (t < NK) {
    float val = cv[t];
    float e = expf(val - cv[0]);
    float s = e;
    #pragma unroll
    for (int off = 16; off >= 1; off >>= 1) s += __shfl_xor(s, off, 32);
    float w = e / s;
    wts[t] = w;
    widx[t] = ci[t];
    dout[OFF_W + bh * NK + t] = w;
    dout[OFF_I + bh * NK + t] = (float)ci[t];
  }
  __syncthreads();

  // memory_reads[b,h,m] = sum_k w_k * mem[b, idx_k, m]
  if (t < NM) {
    float acc = 0.f;
    #pragma unroll 8
    for (int k = 0; k < NK; ++k) {
      unsigned gi = widx[k] < NR ? widx[k] : 0u;  // defensive clamp
      acc += wts[k] * mem[((size_t)b * NR + gi) * NM + t];
    }
    dout[OFF_READS + bh * NM + t] = acc;
  }
}

extern "C" void kernel_launch(void* const* d_in, const int* in_sizes, int n_in,
                              void* d_out, int out_size, void* d_ws, size_t ws_size,
                              hipStream_t stream) {
  const float* x    = (const float*)d_in[0];  // read_inputs (16,512)
  const float* mem  = (const float*)d_in[1];  // mem_state (16,65536,64)
  const float* W    = (const float*)d_in[2];  // (520,512)
  const float* bias = (const float*)d_in[3];  // (520,)
  float* out = (float*)d_out;

  char* ws = (char*)d_ws;
  float* sk_ws   = (float*)ws;                           // 32 KB
  float* str_ws  = (float*)(ws + 32768);                 // 512 B
  float* cv_ws   = (float*)(ws + 65536);                 // 2 MiB
  unsigned* ci_ws = (unsigned*)(ws + 65536 + 2097152);   // 2 MiB

  hipLaunchKernelGGL(k_prep, dim3(NB), dim3(512), 0, stream, x, W, bias, sk_ws, str_ws, out);
  hipLaunchKernelGGL(k_score, dim3(NB * NCHUNK), dim3(256), 0, stream, mem, sk_ws, str_ws, cv_ws, ci_ws);
  hipLaunchKernelGGL(k_final, dim3(NB * NH), dim3(256), 0, stream, mem, cv_ws, ci_ws, out);
}

// Round 3
// 206.902 us; speedup vs baseline: 2.6624x; 2.6624x over previous
//
#include <hip/hip_runtime.h>
#include <hip/hip_bf16.h>
#include <math.h>

// MemoryReader: B=16 H=8 M=64 K=32 R=65536 D_IN=512, OUT_DIM=520
// Outputs (FLOAT32, concatenated): flat_reads[16,512] | read_weights[16,8,32] |
//                                  read_indices[16,8,32] | read_strengths[16,8]
// ws layout (bytes): [0,32768) scaled keys f32; [32768,33280) strengths f32;
//                    [65536, +3.15MiB) cand vals f32; then cand idx u32 (same size).

#define NB 16
#define NH 8
#define NM 64
#define NK 32
#define NR 65536
#define NDIN 512
#define NOUT 520
#define CHUNK 512
#define NCHUNK 128      // R / CHUNK
#define CAND 48         // candidate slots per (chunk, head); target count in [NK, CAND]
#define NCTOT (NCHUNK * CAND)   // 6144 candidates per (b,h)
#define PERTHR (NCTOT / 256)    // 24
#define CAP2 224        // k_final binary-search count upper target
#define SORTN 256       // k_final collection capacity / bitonic size

#define OFF_READS 0
#define OFF_W 8192
#define OFF_I 12288
#define OFF_S 16384

// In-LDS bitonic sort of SORTN (val,idx) pairs, descending by val, ties by ascending idx.
__device__ __forceinline__ void bitonic256(float* cv, unsigned* ci, int t) {
  for (int size = 2; size <= SORTN; size <<= 1) {
    for (int stride = size >> 1; stride > 0; stride >>= 1) {
      __syncthreads();
      int j = t ^ stride;
      if (j > t) {
        float vi = cv[t], vj = cv[j];
        unsigned ii = ci[t], ij = ci[j];
        bool iFirst = (vi > vj) || (vi == vj && ii < ij);
        bool up = ((t & size) == 0);
        if (up != iFirst) { cv[t] = vj; cv[j] = vi; ci[t] = ij; ci[j] = ii; }
      }
    }
  }
  __syncthreads();
}

// Kernel 1: flat = x @ W^T + b; normalize keys per (b,h); emit strengths.
__global__ __launch_bounds__(512) void k_prep(
    const float* __restrict__ x, const float* __restrict__ W,
    const float* __restrict__ bias, float* __restrict__ sk_ws,
    float* __restrict__ str_ws, float* __restrict__ dout) {
  const int b = blockIdx.x, t = threadIdx.x;
  __shared__ float4 xs4[NDIN / 4];
  __shared__ float flat[NOUT];
  if (t < NDIN / 4) xs4[t] = reinterpret_cast<const float4*>(x + (size_t)b * NDIN)[t];
  __syncthreads();
  {
    const float4* Wr = reinterpret_cast<const float4*>(W + (size_t)t * NDIN);
    float acc = 0.f;
    for (int i = 0; i < NDIN / 4; ++i) {
      float4 w4 = Wr[i], v = xs4[i];
      acc += w4.x * v.x + w4.y * v.y + w4.z * v.z + w4.w * v.w;
    }
    flat[t] = acc + bias[t];
  }
  if (t < NOUT - NDIN) {
    const int j = NDIN + t;
    const float4* Wr = reinterpret_cast<const float4*>(W + (size_t)j * NDIN);
    float acc = 0.f;
    for (int i = 0; i < NDIN / 4; ++i) {
      float4 w4 = Wr[i], v = xs4[i];
      acc += w4.x * v.x + w4.y * v.y + w4.z * v.z + w4.w * v.w;
    }
    flat[j] = acc + bias[j];
  }
  __syncthreads();
  // t = h*64 + m; each 64-lane wave is exactly one head h.
  float v = flat[t];
  float ss = v * v;
  #pragma unroll
  for (int off = 32; off >= 1; off >>= 1) ss += __shfl_xor(ss, off, 64);
  float rn = 1.0f / fmaxf(sqrtf(ss), 1e-12f);
  sk_ws[(size_t)b * NDIN + t] = v * rn;
  if (t < NH) {
    float s = flat[NDIN + t];
    str_ws[b * NH + t] = s;
    dout[OFF_S + b * NH + t] = s;
  }
}

// Kernel 2: per (b, 512-row chunk): scores for all 8 heads, then per-head
// wave-private candidate selection (count(>T) in [32,48]) with NO block
// barriers and NO sort. Emits 48 slots per (chunk, head), -INF padded.
__global__ __launch_bounds__(256) void k_score(
    const float* __restrict__ mem, const float* __restrict__ sk_ws,
    const float* __restrict__ str_ws, float* __restrict__ cv_ws,
    unsigned* __restrict__ ci_ws) {
  const int b = blockIdx.x >> 7;
  const int chunk = blockIdx.x & 127;
  const int base = chunk * CHUNK;
  const int t = threadIdx.x;
  const int lane = t & 63, w = t >> 6;

  __shared__ float4 sk4[NH * NM / 4];   // 2 KB
  __shared__ float str[NH];
  __shared__ float sc[NH][CHUNK];       // 16 KB, head-major: conflict-free
  __shared__ float candv[NH][CAND];     // 1.5 KB
  __shared__ unsigned candi[NH][CAND];  // 1.5 KB
  __shared__ unsigned cnt_s[NH];

  if (t < 128) sk4[t] = reinterpret_cast<const float4*>(sk_ws + (size_t)b * NDIN)[t];
  if (t < NH) str[t] = str_ws[b * NH + t];
  __syncthreads();

  // ---- score phase: 2 rows per thread ----
  {
    const float4* m0 = reinterpret_cast<const float4*>(mem + ((size_t)b * NR + base + t) * NM);
    const float4* m1 = reinterpret_cast<const float4*>(mem + ((size_t)b * NR + base + t + 256) * NM);
    float d0a[NH], d1a[NH];
    #pragma unroll
    for (int h = 0; h < NH; ++h) { d0a[h] = 0.f; d1a[h] = 0.f; }
    float ss0 = 0.f, ss1 = 0.f;
    #pragma unroll
    for (int i = 0; i < NM / 4; ++i) {
      float4 va = m0[i], vb = m1[i];
      ss0 += va.x * va.x + va.y * va.y + va.z * va.z + va.w * va.w;
      ss1 += vb.x * vb.x + vb.y * vb.y + vb.z * vb.z + vb.w * vb.w;
      #pragma unroll
      for (int h = 0; h < NH; ++h) {
        float4 s4 = sk4[h * (NM / 4) + i];
        d0a[h] += va.x * s4.x + va.y * s4.y + va.z * s4.z + va.w * s4.w;
        d1a[h] += vb.x * s4.x + vb.y * s4.y + vb.z * s4.z + vb.w * s4.w;
      }
    }
    float rn0 = 1.0f / fmaxf(sqrtf(ss0), 1e-12f);
    float rn1 = 1.0f / fmaxf(sqrtf(ss1), 1e-12f);
    #pragma unroll
    for (int h = 0; h < NH; ++h) {
      sc[h][t] = str[h] * (d0a[h] * rn0);
      sc[h][t + 256] = str[h] * (d1a[h] * rn1);
    }
  }
  __syncthreads();  // the ONLY selection-relevant block barrier

  // ---- selection: wave w handles heads w and w+4, fully wave-private ----
  for (int hh = 0; hh < 2; ++hh) {
    const int h = w + hh * 4;
    float v[8];
    #pragma unroll
    for (int j = 0; j < 8; ++j) v[j] = sc[h][lane + 64 * j];  // stride-1: conflict-free

    float mx = v[0], mn = v[0];
    #pragma unroll
    for (int j = 1; j < 8; ++j) { mx = fmaxf(mx, v[j]); mn = fminf(mn, v[j]); }
    #pragma unroll
    for (int off = 32; off >= 1; off >>= 1) {
      mx = fmaxf(mx, __shfl_xor(mx, off, 64));
      mn = fminf(mn, __shfl_xor(mn, off, 64));
    }

    // binary search for T with count(>T) in [NK, CAND] — shfl-only, no barriers
    float lo = mn - 1.0f, hi = mx, T = lo;
    bool found = false;
    for (int it = 0; it < 48; ++it) {
      float mid = 0.5f * (lo + hi);
      if (!(mid > lo && mid < hi)) break;
      unsigned c = 0;
      #pragma unroll
      for (int j = 0; j < 8; ++j) c += (v[j] > mid) ? 1u : 0u;
      #pragma unroll
      for (int off = 32; off >= 1; off >>= 1) c += __shfl_xor(c, off, 64);
      if (c >= NK) {
        lo = mid;
        if (c <= CAND) { T = mid; found = true; break; }
      } else {
        hi = mid;
      }
    }
    if (!found) T = lo;  // invariant: count(>lo) >= NK

    if (lane == 0) cnt_s[h] = 0u;
    // same-wave LDS ops are ordered: write above completes before atomics below
    #pragma unroll
    for (int j = 0; j < 8; ++j) {
      if (v[j] > T) {
        unsigned p = atomicAdd(&cnt_s[h], 1u);
        if (p < CAND) { candv[h][p] = v[j]; candi[h][p] = (unsigned)(base + lane + 64 * j); }
      }
    }
    unsigned c = cnt_s[h];
    for (unsigned p = c + (unsigned)lane; p < CAND; p += 64u) {
      candv[h][p] = -INFINITY; candi[h][p] = 0x7FFFFFFFu;
    }
    if (lane < CAND) {
      size_t o = (((size_t)(b * NH + h)) * NCHUNK + chunk) * CAND + lane;
      cv_ws[o] = candv[h][lane];
      ci_ws[o] = candi[h][lane];
    }
  }
}

// Kernel 3: per (b,h): exact global top-32 over the 6144 chunk candidates
// (held in registers) via value-domain binary search + bitonic sort, then
// softmax, gather memory rows, write remaining outputs.
__global__ __launch_bounds__(256) void k_final(
    const float* __restrict__ mem, const float* __restrict__ cv_ws,
    const unsigned* __restrict__ ci_ws, float* __restrict__ dout) {
  const int bh = blockIdx.x;
  const int b = bh >> 3;
  const int t = threadIdx.x;
  const int lane = t & 63, wid = t >> 6;

  __shared__ float cv[SORTN];
  __shared__ unsigned ci[SORTN];
  __shared__ float red[8];
  __shared__ unsigned ucnt;
  __shared__ float wts[NK];
  __shared__ unsigned widx[NK];

  const float* CV = cv_ws + (size_t)bh * NCTOT;
  const unsigned* CI = ci_ws + (size_t)bh * NCTOT;

  // All candidates in registers, coalesced loads.
  float v[PERTHR];
  unsigned vi[PERTHR];
  #pragma unroll
  for (int i = 0; i < PERTHR; ++i) {
    v[i] = CV[i * 256 + t];
    vi[i] = CI[i * 256 + t];
  }

  // min over FINITE values only (-INF pads would poison the search range)
  float mx = -INFINITY, mn = INFINITY;
  #pragma unroll
  for (int i = 0; i < PERTHR; ++i) {
    mx = fmaxf(mx, v[i]);
    if (v[i] > -1e37f) mn = fminf(mn, v[i]);
  }
  #pragma unroll
  for (int off = 32; off >= 1; off >>= 1) {
    mx = fmaxf(mx, __shfl_xor(mx, off, 64));
    mn = fminf(mn, __shfl_xor(mn, off, 64));
  }
  if (lane == 0) { red[wid] = mx; red[4 + wid] = mn; }
  __syncthreads();
  float bmax = fmaxf(fmaxf(red[0], red[1]), fmaxf(red[2], red[3]));
  float bmin = fminf(fminf(red[4], red[5]), fminf(red[6], red[7]));
  __syncthreads();

  // binary search for T with count(>T) in [NK, CAP2]
  float lo = bmin - 1.0f, hi = bmax;
  float T = lo;
  bool found = false;
  for (int it = 0; it < 60; ++it) {
    float mid = 0.5f * (lo + hi);
    if (!(mid > lo && mid < hi)) break;
    if (t == 0) ucnt = 0u;
    __syncthreads();
    unsigned c = 0;
    #pragma unroll
    for (int i = 0; i < PERTHR; ++i) c += (v[i] > mid) ? 1u : 0u;
    #pragma unroll
    for (int off = 32; off >= 1; off >>= 1) c += __shfl_xor(c, off, 64);
    if (lane == 0) atomicAdd(&ucnt, c);
    __syncthreads();
    unsigned cnt = ucnt;
    __syncthreads();
    if (cnt >= NK) {
      lo = mid;
      if (cnt <= CAP2) { T = mid; found = true; break; }
    } else {
      hi = mid;
    }
  }
  if (!found) T = lo;  // count(>lo) >= NK invariant

  if (t == 0) ucnt = 0u;
  __syncthreads();
  #pragma unroll
  for (int i = 0; i < PERTHR; ++i) {
    if (v[i] > T) {
      unsigned p = atomicAdd(&ucnt, 1u);
      if (p < SORTN) { cv[p] = v[i]; ci[p] = vi[i]; }
    }
  }
  __syncthreads();
  unsigned cnt = ucnt < SORTN ? ucnt : (unsigned)SORTN;
  if ((unsigned)t >= cnt) { cv[t] = -INFINITY; ci[t] = 0x7FFFFFFFu; }
  bitonic256(cv, ci, t);

  // softmax over the sorted top-32 (cv[0] is the max)
  if (t < NK) {
    float val = cv[t];
    float e = expf(val - cv[0]);
    float s = e;
    #pragma unroll
    for (int off = 16; off >= 1; off >>= 1) s += __shfl_xor(s, off, 32);
    float w = e / s;
    wts[t] = w;
    widx[t] = ci[t];
    dout[OFF_W + bh * NK + t] = w;
    dout[OFF_I + bh * NK + t] = (float)ci[t];
  }
  __syncthreads();

  // memory_reads[b,h,m] = sum_k w_k * mem[b, idx_k, m]
  if (t < NM) {
    float acc = 0.f;
    #pragma unroll 8
    for (int k = 0; k < NK; ++k) {
      unsigned gi = widx[k] < NR ? widx[k] : 0u;  // defensive clamp
      acc += wts[k] * mem[((size_t)b * NR + gi) * NM + t];
    }
    dout[OFF_READS + bh * NM + t] = acc;
  }
}

extern "C" void kernel_launch(void* const* d_in, const int* in_sizes, int n_in,
                              void* d_out, int out_size, void* d_ws, size_t ws_size,
                              hipStream_t stream) {
  const float* x    = (const float*)d_in[0];  // read_inputs (16,512)
  const float* mem  = (const float*)d_in[1];  // mem_state (16,65536,64)
  const float* W    = (const float*)d_in[2];  // (520,512)
  const float* bias = (const float*)d_in[3];  // (520,)
  float* out = (float*)d_out;

  char* ws = (char*)d_ws;
  float* sk_ws    = (float*)ws;                   // 32 KB
  float* str_ws   = (float*)(ws + 32768);         // 512 B
  // candidates: 128 bh * 6144 * 4 B = 3.15 MB each
  const size_t cand_bytes = (size_t)NB * NH * NCTOT * 4;
  float* cv_ws    = (float*)(ws + 65536);
  unsigned* ci_ws = (unsigned*)(ws + 65536 + cand_bytes);

  hipLaunchKernelGGL(k_prep, dim3(NB), dim3(512), 0, stream, x, W, bias, sk_ws, str_ws, out);
  hipLaunchKernelGGL(k_score, dim3(NB * NCHUNK), dim3(256), 0, stream, mem, sk_ws, str_ws, cv_ws, ci_ws);
  hipLaunchKernelGGL(k_final, dim3(NB * NH), dim3(256), 0, stream, mem, cv_ws, ci_ws, out);
}

// Round 4
// 133.342 us; speedup vs baseline: 4.1311x; 1.5517x over previous
//
#include <hip/hip_runtime.h>
#include <hip/hip_bf16.h>
#include <math.h>

// MemoryReader: B=16 H=8 M=64 K=32 R=65536 D_IN=512, OUT_DIM=520
// Outputs (FLOAT32, concatenated): flat_reads[16,512] | read_weights[16,8,32] |
//                                  read_indices[16,8,32] | read_strengths[16,8]

#define NB 16
#define NH 8
#define NM 64
#define NK 32
#define NR 65536
#define NDIN 512
#define NOUT 520
#define CHUNK 512
#define NCHUNK 128      // R / CHUNK
#define CAND 48         // candidate slots per (chunk, head); count target in [NK, CAND]
#define NCTOT (NCHUNK * CAND)   // 6144 candidates per (b,h)
#define FPT (NCTOT / 256)       // 24 per thread in k_final
#define STAGE1 (4 * CAND)       // 192 stage-1 survivors in k_final

#define OFF_READS 0
#define OFF_W 8192
#define OFF_I 12288
#define OFF_S 16384

// Kernel 1: flat = x @ W^T + b; normalize keys per (b,h); emit strengths.
__global__ __launch_bounds__(512) void k_prep(
    const float* __restrict__ x, const float* __restrict__ W,
    const float* __restrict__ bias, float* __restrict__ sk_ws,
    float* __restrict__ str_ws, float* __restrict__ dout) {
  const int b = blockIdx.x, t = threadIdx.x;
  __shared__ float4 xs4[NDIN / 4];
  __shared__ float flat[NOUT];
  if (t < NDIN / 4) xs4[t] = reinterpret_cast<const float4*>(x + (size_t)b * NDIN)[t];
  __syncthreads();
  {
    const float4* Wr = reinterpret_cast<const float4*>(W + (size_t)t * NDIN);
    float acc = 0.f;
    for (int i = 0; i < NDIN / 4; ++i) {
      float4 w4 = Wr[i], v = xs4[i];
      acc += w4.x * v.x + w4.y * v.y + w4.z * v.z + w4.w * v.w;
    }
    flat[t] = acc + bias[t];
  }
  if (t < NOUT - NDIN) {
    const int j = NDIN + t;
    const float4* Wr = reinterpret_cast<const float4*>(W + (size_t)j * NDIN);
    float acc = 0.f;
    for (int i = 0; i < NDIN / 4; ++i) {
      float4 w4 = Wr[i], v = xs4[i];
      acc += w4.x * v.x + w4.y * v.y + w4.z * v.z + w4.w * v.w;
    }
    flat[j] = acc + bias[j];
  }
  __syncthreads();
  // t = h*64 + m; each 64-lane wave is exactly one head h.
  float v = flat[t];
  float ss = v * v;
  #pragma unroll
  for (int off = 32; off >= 1; off >>= 1) ss += __shfl_xor(ss, off, 64);
  float rn = 1.0f / fmaxf(sqrtf(ss), 1e-12f);
  sk_ws[(size_t)b * NDIN + t] = v * rn;
  if (t < NH) {
    float s = flat[NDIN + t];
    str_ws[b * NH + t] = s;
    dout[OFF_S + b * NH + t] = s;
  }
}

// Kernel 2: per (b, 512-row chunk): 1 row/thread scores for all 8 heads,
// then per-wave (1 head each) shfl-only candidate selection, count in [32,48].
// __launch_bounds__(512,8): cap VGPR<=64 -> 8 waves/SIMD for latency hiding.
__global__ __launch_bounds__(512, 8) void k_score(
    const float* __restrict__ mem, const float* __restrict__ sk_ws,
    const float* __restrict__ str_ws, float* __restrict__ cv_ws,
    unsigned* __restrict__ ci_ws) {
  const int b = blockIdx.x >> 7;
  const int chunk = blockIdx.x & 127;
  const int base = chunk * CHUNK;
  const int t = threadIdx.x;           // 0..511: one memory row each
  const int lane = t & 63, w = t >> 6; // 8 waves

  __shared__ float4 sk4[NH * NM / 4];   // 2 KB
  __shared__ float str[NH];
  __shared__ float sc[NH][CHUNK];       // 16 KB, head-major: conflict-free
  __shared__ float candv[NH][CAND];
  __shared__ unsigned candi[NH][CAND];
  __shared__ unsigned cnt_s[NH];

  if (t < 128) sk4[t] = reinterpret_cast<const float4*>(sk_ws + (size_t)b * NDIN)[t];
  if (t < NH) str[t] = str_ws[b * NH + t];
  __syncthreads();

  // ---- score phase: one row per thread ----
  {
    const float4* m0 = reinterpret_cast<const float4*>(mem + ((size_t)b * NR + base + t) * NM);
    float acc[NH];
    #pragma unroll
    for (int h = 0; h < NH; ++h) acc[h] = 0.f;
    float ss = 0.f;
    #pragma unroll 8
    for (int i = 0; i < NM / 4; ++i) {
      float4 va = m0[i];
      ss += va.x * va.x + va.y * va.y + va.z * va.z + va.w * va.w;
      #pragma unroll
      for (int h = 0; h < NH; ++h) {
        float4 s4 = sk4[h * (NM / 4) + i];
        acc[h] += va.x * s4.x + va.y * s4.y + va.z * s4.z + va.w * s4.w;
      }
    }
    float rn = 1.0f / fmaxf(sqrtf(ss), 1e-12f);
    #pragma unroll
    for (int h = 0; h < NH; ++h) sc[h][t] = str[h] * (acc[h] * rn);
  }
  __syncthreads();  // the ONLY selection-relevant block barrier

  // ---- selection: wave w handles head w, fully wave-private ----
  {
    const int h = w;
    float v[8];
    #pragma unroll
    for (int j = 0; j < 8; ++j) v[j] = sc[h][lane + 64 * j];  // 2-way bank alias: free

    float mx = v[0], mn = v[0];
    #pragma unroll
    for (int j = 1; j < 8; ++j) { mx = fmaxf(mx, v[j]); mn = fminf(mn, v[j]); }
    #pragma unroll
    for (int off = 32; off >= 1; off >>= 1) {
      mx = fmaxf(mx, __shfl_xor(mx, off, 64));
      mn = fminf(mn, __shfl_xor(mn, off, 64));
    }

    // binary search for T with count(>T) in [NK, CAND] — shfl-only, no barriers
    float lo = mn - 1.0f, hi = mx, T = lo;
    bool found = false;
    for (int it = 0; it < 48; ++it) {
      float mid = 0.5f * (lo + hi);
      if (!(mid > lo && mid < hi)) break;
      unsigned c = 0;
      #pragma unroll
      for (int j = 0; j < 8; ++j) c += (v[j] > mid) ? 1u : 0u;
      #pragma unroll
      for (int off = 32; off >= 1; off >>= 1) c += __shfl_xor(c, off, 64);
      if (c >= NK) {
        lo = mid;
        if (c <= CAND) { T = mid; found = true; break; }
      } else {
        hi = mid;
      }
    }
    if (!found) T = lo;  // invariant: count(>lo) >= NK

    if (lane == 0) cnt_s[h] = 0u;
    // same-wave LDS ops are ordered: the write above precedes the atomics
    #pragma unroll
    for (int j = 0; j < 8; ++j) {
      if (v[j] > T) {
        unsigned p = atomicAdd(&cnt_s[h], 1u);
        if (p < CAND) { candv[h][p] = v[j]; candi[h][p] = (unsigned)(base + lane + 64 * j); }
      }
    }
    unsigned c = cnt_s[h];
    for (unsigned p = c + (unsigned)lane; p < CAND; p += 64u) {
      candv[h][p] = -INFINITY; candi[h][p] = 0x7F000000u + p;  // distinct pad ids
    }
    if (lane < CAND) {
      size_t o = (((size_t)(b * NH + h)) * NCHUNK + chunk) * CAND + lane;
      cv_ws[o] = candv[h][lane];
      ci_ws[o] = candi[h][lane];
    }
  }
}

// Kernel 3: per (b,h): stage-1 per-wave top-[32,48] supersets (shfl-only),
// stage-2 rank-based exact sorted top-32 over <=192 survivors, then softmax +
// gather. ~4 block barriers total.
__global__ __launch_bounds__(256) void k_final(
    const float* __restrict__ mem, const float* __restrict__ cv_ws,
    const unsigned* __restrict__ ci_ws, float* __restrict__ dout) {
  const int bh = blockIdx.x;
  const int b = bh >> 3;
  const int t = threadIdx.x;
  const int lane = t & 63, w = t >> 6;  // 4 waves

  __shared__ float cv[STAGE1];
  __shared__ unsigned ci[STAGE1];
  __shared__ unsigned cnt_s[4];
  __shared__ float fv[NK];
  __shared__ unsigned fi[NK];
  __shared__ float wts[NK];
  __shared__ unsigned widx[NK];

  const float* CV = cv_ws + (size_t)bh * NCTOT;
  const unsigned* CI = ci_ws + (size_t)bh * NCTOT;

  // wave w owns candidates {i*256 + t : i<24} (t in wave's lane range)
  float v[FPT];
  unsigned vi[FPT];
  #pragma unroll
  for (int i = 0; i < FPT; ++i) {
    v[i] = CV[i * 256 + t];
    vi[i] = CI[i * 256 + t];
  }

  // wave-local range (exclude -INF pads from min)
  float mx = -INFINITY, mn = INFINITY;
  #pragma unroll
  for (int i = 0; i < FPT; ++i) {
    mx = fmaxf(mx, v[i]);
    if (v[i] > -1e37f) mn = fminf(mn, v[i]);
  }
  #pragma unroll
  for (int off = 32; off >= 1; off >>= 1) {
    mx = fmaxf(mx, __shfl_xor(mx, off, 64));
    mn = fminf(mn, __shfl_xor(mn, off, 64));
  }

  // wave-local binary search: count(>T) in [NK, CAND] over this wave's 1536
  float lo = mn - 1.0f, hi = mx, T = lo;
  bool found = false;
  for (int it = 0; it < 48; ++it) {
    float mid = 0.5f * (lo + hi);
    if (!(mid > lo && mid < hi)) break;
    unsigned c = 0;
    #pragma unroll
    for (int i = 0; i < FPT; ++i) c += (v[i] > mid) ? 1u : 0u;
    #pragma unroll
    for (int off = 32; off >= 1; off >>= 1) c += __shfl_xor(c, off, 64);
    if (c >= NK) {
      lo = mid;
      if (c <= CAND) { T = mid; found = true; break; }
    } else {
      hi = mid;
    }
  }
  if (!found) T = lo;

  if (lane == 0) cnt_s[w] = 0u;
  #pragma unroll
  for (int i = 0; i < FPT; ++i) {
    if (v[i] > T) {
      unsigned p = atomicAdd(&cnt_s[w], 1u);
      if (p < CAND) { cv[w * CAND + p] = v[i]; ci[w * CAND + p] = vi[i]; }
    }
  }
  {
    unsigned c = cnt_s[w];
    for (unsigned p = c + (unsigned)lane; p < CAND; p += 64u) {
      cv[w * CAND + p] = -INFINITY;
      ci[w * CAND + p] = 0x7F100000u + w * CAND + p;  // distinct pad ids
    }
  }
  __syncthreads();

  // stage 2: exact rank of each survivor; top-32 land sorted in fv/fi
  if (t < STAGE1) {
    float myv = cv[t];
    unsigned myi = ci[t];
    int rank = 0;
    for (int j = 0; j < STAGE1; ++j) {
      float vj = cv[j];
      unsigned ij = ci[j];
      rank += ((vj > myv) || (vj == myv && ij < myi)) ? 1 : 0;
    }
    if (rank < NK) { fv[rank] = myv; fi[rank] = myi; }
  }
  __syncthreads();

  // softmax over the sorted top-32 (fv[0] is the max)
  if (t < NK) {
    float e = expf(fv[t] - fv[0]);
    float s = e;
    #pragma unroll
    for (int off = 16; off >= 1; off >>= 1) s += __shfl_xor(s, off, 32);
    float wgt = e / s;
    wts[t] = wgt;
    widx[t] = fi[t];
    dout[OFF_W + bh * NK + t] = wgt;
    dout[OFF_I + bh * NK + t] = (float)fi[t];
  }
  __syncthreads();

  // memory_reads[b,h,m] = sum_k w_k * mem[b, idx_k, m]
  if (t < NM) {
    float acc = 0.f;
    #pragma unroll 8
    for (int k = 0; k < NK; ++k) {
      unsigned gi = widx[k] < NR ? widx[k] : 0u;  // defensive clamp
      acc += wts[k] * mem[((size_t)b * NR + gi) * NM + t];
    }
    dout[OFF_READS + bh * NM + t] = acc;
  }
}

extern "C" void kernel_launch(void* const* d_in, const int* in_sizes, int n_in,
                              void* d_out, int out_size, void* d_ws, size_t ws_size,
                              hipStream_t stream) {
  const float* x    = (const float*)d_in[0];  // read_inputs (16,512)
  const float* mem  = (const float*)d_in[1];  // mem_state (16,65536,64)
  const float* W    = (const float*)d_in[2];  // (520,512)
  const float* bias = (const float*)d_in[3];  // (520,)
  float* out = (float*)d_out;

  char* ws = (char*)d_ws;
  float* sk_ws    = (float*)ws;                   // 32 KB
  float* str_ws   = (float*)(ws + 32768);         // 512 B
  const size_t cand_bytes = (size_t)NB * NH * NCTOT * 4;  // 3.15 MB
  float* cv_ws    = (float*)(ws + 65536);
  unsigned* ci_ws = (unsigned*)(ws + 65536 + cand_bytes);

  hipLaunchKernelGGL(k_prep, dim3(NB), dim3(512), 0, stream, x, W, bias, sk_ws, str_ws, out);
  hipLaunchKernelGGL(k_score, dim3(NB * NCHUNK), dim3(512), 0, stream, mem, sk_ws, str_ws, cv_ws, ci_ws);
  hipLaunchKernelGGL(k_final, dim3(NB * NH), dim3(256), 0, stream, mem, cv_ws, ci_ws, out);
}